// Round 1
// baseline (11019.278 us; speedup 1.0000x reference)
//
#include <hip/hip_runtime.h>
#include <math.h>
#include <stdint.h>

#define AG __HIP_MEMORY_SCOPE_AGENT

__device__ __forceinline__ void sigrel(unsigned* c) {
  __hip_atomic_fetch_add(c, 1u, __ATOMIC_RELEASE, AG);
}

__device__ __forceinline__ void waitge(unsigned* c, unsigned tgt) {
  if (threadIdx.x == 0) {
    while ((int)(__hip_atomic_load(c, __ATOMIC_RELAXED, AG) - tgt) < 0)
      __builtin_amdgcn_s_sleep(1);
    (void)__hip_atomic_load(c, __ATOMIC_ACQUIRE, AG);
  }
  __syncthreads();
}

__device__ __forceinline__ float act_apply(int act, float v) {
  if (act == 0) {  // gelu (tanh approximation, jax.nn.gelu default)
    float v3 = v * v * v;
    return 0.5f * v * (1.0f + tanhf(0.7978845608028654f * (v + 0.044715f * v3)));
  }
  if (act == 1) return tanhf(v);
  return v;
}

// ---------------- P4: rows=4 matmul stage -------------------------------
// One WG computes a 64-col tile for K-chunk [k0,k0+chunk).
// threads: j = tid&63 (col), kq = tid>>6 (k quarter). LDS z stage + LDS reduce.
// If KC>1: writes partial, last-arriving WG (per tile) reduces deterministically.
template <class ZL, class ST>
__device__ void p4(const float* __restrict__ W, int ldw, const float* __restrict__ bias,
                   int c0, int k0, int chunk, int act,
                   int KC, int kc, unsigned* kcCnt, float* part,
                   unsigned* stageCnt, float* lds, unsigned* sflag,
                   ZL&& zload, ST&& store) {
  const int tid = threadIdx.x;
  const int j = tid & 63, kq = tid >> 6;
  // stage z[4][chunk] into LDS
  for (int i = tid; i < 4 * chunk; i += 256) {
    int b = i / chunk, kk = i - b * chunk;
    lds[i] = zload(b, k0 + kk);
  }
  __syncthreads();
  const int sub = chunk >> 2;
  float a0 = 0.f, a1 = 0.f, a2 = 0.f, a3 = 0.f;
  const float* wp = W + (size_t)(k0 + kq * sub) * ldw + (c0 + j);
  const float* z0 = lds + kq * sub;
  const float* z1 = z0 + chunk;
  const float* z2 = z1 + chunk;
  const float* z3 = z2 + chunk;
#pragma unroll 4
  for (int kk = 0; kk < sub; ++kk) {
    float w = wp[(size_t)kk * ldw];
    a0 = fmaf(z0[kk], w, a0);
    a1 = fmaf(z1[kk], w, a1);
    a2 = fmaf(z2[kk], w, a2);
    a3 = fmaf(z3[kk], w, a3);
  }
  __syncthreads();
  float* red = lds;  // [256][4]
  red[tid * 4 + 0] = a0; red[tid * 4 + 1] = a1;
  red[tid * 4 + 2] = a2; red[tid * 4 + 3] = a3;
  __syncthreads();
  const int jj = tid >> 2, b = tid & 3;
  float v = red[jj * 4 + b] + red[256 + jj * 4 + b] + red[512 + jj * 4 + b] + red[768 + jj * 4 + b];
  if (KC == 1) {
    v += bias[c0 + jj];
    v = act_apply(act, v);
    store(b, c0 + jj, v);
    __syncthreads();
    if (tid == 0) sigrel(stageCnt);
  } else {
    part[kc * 256 + jj * 4 + b] = v;
    __syncthreads();
    if (tid == 0) {
      unsigned old = __hip_atomic_fetch_add(kcCnt, 1u, __ATOMIC_ACQ_REL, AG);
      *sflag = (old == (unsigned)(KC - 1)) ? 1u : 0u;
    }
    __syncthreads();
    if (*sflag) {
      float s = 0.f;
      for (int q = 0; q < KC; ++q) s += part[q * 256 + jj * 4 + b];
      s += bias[c0 + jj];
      s = act_apply(act, s);
      store(b, c0 + jj, s);
      if (tid == 0) __hip_atomic_store(kcCnt, 0u, __ATOMIC_RELAXED, AG);
      __syncthreads();
      if (tid == 0) sigrel(stageCnt);
    }
  }
  __syncthreads();
}

// ---------------- P64: rows=64 tiled GEMM stage (FF) --------------------
// 64x64 output tile, K-blocks of 16 staged in LDS, 4x4 register tile/thread.
template <class ZL, class ST>
__device__ void p64(const float* __restrict__ W, int ldw, const float* __restrict__ bias,
                    int c0, int k0, int k1, int act,
                    int KC, int kc, unsigned* kcCnt, float* part,
                    unsigned* stageCnt, float* lds, unsigned* sflag,
                    ZL&& zload, ST&& store) {
  const int tid = threadIdx.x;
  const int tj = tid & 15, tr = tid >> 4;
  float acc[4][4];
#pragma unroll
  for (int r = 0; r < 4; ++r)
#pragma unroll
    for (int c = 0; c < 4; ++c) acc[r][c] = 0.f;
  float* Wl = lds;          // [16][64]
  float* Zl = lds + 1024;   // [64][17]
  const int wk = tid >> 4, wc = (tid & 15) * 4;
  const int zrow = tid & 63, zk = (tid >> 6) * 4;
  for (int kb = k0; kb < k1; kb += 16) {
    __syncthreads();
    *(float4*)&Wl[wk * 64 + wc] = *(const float4*)(W + (size_t)(kb + wk) * ldw + c0 + wc);
    Zl[zrow * 17 + zk + 0] = zload(zrow, kb + zk + 0);
    Zl[zrow * 17 + zk + 1] = zload(zrow, kb + zk + 1);
    Zl[zrow * 17 + zk + 2] = zload(zrow, kb + zk + 2);
    Zl[zrow * 17 + zk + 3] = zload(zrow, kb + zk + 3);
    __syncthreads();
#pragma unroll
    for (int kk = 0; kk < 16; ++kk) {
      float4 w4 = *(float4*)&Wl[kk * 64 + tj * 4];
      float zr0 = Zl[(tr * 4 + 0) * 17 + kk];
      float zr1 = Zl[(tr * 4 + 1) * 17 + kk];
      float zr2 = Zl[(tr * 4 + 2) * 17 + kk];
      float zr3 = Zl[(tr * 4 + 3) * 17 + kk];
      acc[0][0] = fmaf(zr0, w4.x, acc[0][0]); acc[0][1] = fmaf(zr0, w4.y, acc[0][1]);
      acc[0][2] = fmaf(zr0, w4.z, acc[0][2]); acc[0][3] = fmaf(zr0, w4.w, acc[0][3]);
      acc[1][0] = fmaf(zr1, w4.x, acc[1][0]); acc[1][1] = fmaf(zr1, w4.y, acc[1][1]);
      acc[1][2] = fmaf(zr1, w4.z, acc[1][2]); acc[1][3] = fmaf(zr1, w4.w, acc[1][3]);
      acc[2][0] = fmaf(zr2, w4.x, acc[2][0]); acc[2][1] = fmaf(zr2, w4.y, acc[2][1]);
      acc[2][2] = fmaf(zr2, w4.z, acc[2][2]); acc[2][3] = fmaf(zr2, w4.w, acc[2][3]);
      acc[3][0] = fmaf(zr3, w4.x, acc[3][0]); acc[3][1] = fmaf(zr3, w4.y, acc[3][1]);
      acc[3][2] = fmaf(zr3, w4.z, acc[3][2]); acc[3][3] = fmaf(zr3, w4.w, acc[3][3]);
    }
  }
  __syncthreads();
  if (KC == 1) {
#pragma unroll
    for (int r = 0; r < 4; ++r)
#pragma unroll
      for (int c = 0; c < 4; ++c) {
        int col = c0 + tj * 4 + c;
        float v = acc[r][c] + bias[col];
        v = act_apply(act, v);
        store(tr * 4 + r, col, v);
      }
    __syncthreads();
    if (tid == 0) sigrel(stageCnt);
  } else {
    float* pp = part + kc * 4096;
#pragma unroll
    for (int r = 0; r < 4; ++r)
#pragma unroll
      for (int c = 0; c < 4; ++c) pp[(tr * 4 + r) * 64 + tj * 4 + c] = acc[r][c];
    __syncthreads();
    if (tid == 0) {
      unsigned old = __hip_atomic_fetch_add(kcCnt, 1u, __ATOMIC_ACQ_REL, AG);
      *sflag = (old == (unsigned)(KC - 1)) ? 1u : 0u;
    }
    __syncthreads();
    if (*sflag) {
      for (int r = 0; r < 4; ++r)
        for (int c = 0; c < 4; ++c) {
          int idx = (tr * 4 + r) * 64 + tj * 4 + c;
          float s = 0.f;
          for (int q = 0; q < KC; ++q) s += part[q * 4096 + idx];
          int col = c0 + tj * 4 + c;
          s += bias[col];
          s = act_apply(act, s);
          store(tr * 4 + r, col, s);
        }
      if (tid == 0) __hip_atomic_store(kcCnt, 0u, __ATOMIC_RELAXED, AG);
      __syncthreads();
      if (tid == 0) sigrel(stageCnt);
    }
  }
  __syncthreads();
}

struct P {
  const float *x;
  const float *e0W0, *e0b0, *e0W1, *e0b1, *e0W2, *e0b2;
  const float *erW0, *erb0, *erW1, *erb1, *erW2, *erb2;
  const float *ffW0, *ffb0, *ffW1, *ffb1;
  const float *dW0, *db0, *dWh, *dbh, *dWo, *dbo;
  float *S, *h1, *h2, *g, *eo, *hd0, *hd1, *dob, *pLvl, *pF2, *pD;
  unsigned *aT, *bT, *cT, *ffg, *ffo, *dcnt, *kcA, *kcB, *kcC, *kcF2, *kcD, *kcDo;
  float* out;
};

// S layout: S[r][t][e][b][512]
#define S_IDX(r, t, e, b) ((size_t)((((r)*16 + (t)) * 16 + (e)) * 4 + (b)) * 512)

__global__ __launch_bounds__(256, 2) void hrnn(P p) {
  __shared__ __align__(16) float lds[2432];
  __shared__ unsigned sflag;
  const int w = blockIdx.x;
  const int e = w >> 5, slot = w & 31;
  const int tileL = slot >> 2, kcL = slot & 3;

  // ================= ENCODER LEVELS (level-sequential, per-e pipelines) ===
  for (int r = 0; r < 4; ++r) {
    const float *W0, *B0, *W1, *B1, *W2, *B2;
    int K0;
    if (r == 0) {
      W0 = p.e0W0 + (size_t)e * 544 * 512; B0 = p.e0b0 + e * 512;
      W1 = p.e0W1 + (size_t)e * 512 * 512; B1 = p.e0b1 + e * 512;
      W2 = p.e0W2 + (size_t)e * 512 * 512; B2 = p.e0b2 + e * 512;
      K0 = 544;
    } else {
      int ri = (r - 1) * 16 + e;
      W0 = p.erW0 + (size_t)ri * 1024 * 512; B0 = p.erb0 + (size_t)ri * 512;
      W1 = p.erW1 + (size_t)ri * 512 * 512;  B1 = p.erb1 + (size_t)ri * 512;
      W2 = p.erW2 + (size_t)ri * 512 * 512;  B2 = p.erb2 + (size_t)ri * 512;
      K0 = 1024;
    }
    const int chunk0 = K0 >> 2;
    for (int t = 0; t < 16; ++t) {
      unsigned inst = (unsigned)(r * 16 + t);
      waitge(p.cT + e, 8u * inst);
      {  // stage A: z = [prev, state] -> h1 (gelu)
        const float* xg = p.x; const float* Sp = p.S;
        const int tt = t, rr = r, ee = e;
        auto zl = [=](int b, int k) -> float {
          if (rr == 0) {
            if (k < 32) return xg[(b * 16 + tt) * 32 + k];
            return tt ? Sp[S_IDX(0, tt - 1, ee, b) + (k - 32)] : 0.f;
          } else {
            if (k < 512) return Sp[S_IDX(rr - 1, tt, ee, b) + k];
            return tt ? Sp[S_IDX(rr, tt - 1, ee, b) + (k - 512)] : 0.f;
          }
        };
        float* h1 = p.h1; const int ee2 = e;
        auto st = [=](int b, int col, float v) { h1[(ee2 * 4 + b) * 512 + col] = v; };
        p4(W0, 512, B0, tileL * 64, kcL * chunk0, chunk0, 0, 4, kcL,
           p.kcA + (e * 8 + tileL), p.pLvl + (size_t)(e * 8 + tileL) * 1024,
           p.aT + e, lds, &sflag, zl, st);
      }
      waitge(p.aT + e, 8u * (inst + 1));
      {  // stage B: h1 -> h2 (gelu)
        const float* h1 = p.h1; const int ee = e;
        auto zl = [=](int b, int k) -> float { return h1[(ee * 4 + b) * 512 + k]; };
        float* h2 = p.h2;
        auto st = [=](int b, int col, float v) { h2[(ee * 4 + b) * 512 + col] = v; };
        p4(W1, 512, B1, tileL * 64, kcL * 128, 128, 0, 4, kcL,
           p.kcB + (e * 8 + tileL), p.pLvl + (size_t)(e * 8 + tileL) * 1024,
           p.bT + e, lds, &sflag, zl, st);
      }
      waitge(p.bT + e, 8u * (inst + 1));
      {  // stage C: h2 -> S (tanh)
        const float* h2 = p.h2; const int ee = e, tt = t, rr = r;
        auto zl = [=](int b, int k) -> float { return h2[(ee * 4 + b) * 512 + k]; };
        float* Sp = p.S;
        auto st = [=](int b, int col, float v) { Sp[S_IDX(rr, tt, ee, b) + col] = v; };
        p4(W2, 512, B2, tileL * 64, kcL * 128, 128, 1, 4, kcL,
           p.kcC + (e * 8 + tileL), p.pLvl + (size_t)(e * 8 + tileL) * 1024,
           p.cT + e, lds, &sflag, zl, st);
      }
    }
  }

  // ================= FFNN (batched over all 64 (t,b) rows) ================
  waitge(p.cT + e, 512u);
  {  // FF1: cat(S0..S3) @ ffW0 -> g (gelu), K=2048, 32 col-tiles per e
    const float* Sp = p.S; const int ee = e;
    auto zl = [=](int row, int k) -> float {
      int tt = row >> 2, b = row & 3, seg = k >> 9;
      return Sp[S_IDX(seg, tt, ee, b) + (k & 511)];
    };
    float* g = p.g;
    auto st = [=](int row, int col, float v) { g[(ee * 64 + row) * 2048 + col] = v; };
    p64(p.ffW0 + (size_t)e * 2048 * 2048, 2048, p.ffb0 + e * 2048, slot * 64, 0, 2048, 0,
        1, 0, (unsigned*)0, (float*)0, p.ffg + e, lds, &sflag, zl, st);
  }
  waitge(p.ffg + e, 32u);
  {  // FF2: g @ ffW1 -> encout (linear), K=2048 split 4
    const int ct = slot >> 2, kc2 = slot & 3;
    const float* g = p.g; const int ee = e;
    auto zl = [=](int row, int k) -> float { return g[(ee * 64 + row) * 2048 + k]; };
    float* eo = p.eo;
    auto st = [=](int row, int col, float v) {
      int tt = row >> 2, b = row & 3;
      eo[(size_t)((tt * 16 + ee) * 4 + b) * 512 + col] = v;
    };
    p64(p.ffW1 + (size_t)e * 2048 * 512, 512, p.ffb1 + e * 512, ct * 64,
        kc2 * 512, (kc2 + 1) * 512, 2, 4, kc2,
        p.kcF2 + (e * 8 + ct), p.pF2 + (size_t)(e * 8 + ct) * 16384,
        p.ffo, lds, &sflag, zl, st);
  }

  // ================= DECODER (sequential over t) ==========================
  waitge(p.ffo, 128u);
  {
    const int tile = w >> 4, kD = w & 15;    // layers 0..4: 32 tiles x 16 kc
    const int tileO = w >> 5, kO = w & 31;   // out: 16 tiles x 32 kc
    for (int t = 0; t < 16; ++t) {
      waitge(p.dcnt + 5, 16u * t);
      {  // layer 0: z = [encout(8192), dec_s(1024)], K=9216 split 16
        const float* eo = p.eo; const float* dob = p.dob; const int tt = t;
        auto zl = [=](int b, int k) -> float {
          if (k < 8192) {
            int ee = k >> 9;
            return eo[(size_t)((tt * 16 + ee) * 4 + b) * 512 + (k & 511)];
          }
          return tt ? dob[b * 1024 + (k - 8192)] : 0.f;
        };
        float* hd = p.hd0;
        auto st = [=](int b, int col, float v) { hd[b * 2048 + col] = v; };
        p4(p.dW0, 2048, p.db0, tile * 64, kD * 576, 576, 0, 16, kD,
           p.kcD + tile, p.pD + (size_t)tile * 4096, p.dcnt + 0, lds, &sflag, zl, st);
      }
      for (int l = 1; l <= 4; ++l) {
        waitge(p.dcnt + (l - 1), 32u * (t + 1));
        const float* hin = (l & 1) ? p.hd0 : p.hd1;
        float* hout = (l & 1) ? p.hd1 : p.hd0;
        auto zl = [=](int b, int k) -> float { return hin[b * 2048 + k]; };
        auto st = [=](int b, int col, float v) { hout[b * 2048 + col] = v; };
        p4(p.dWh + (size_t)(l - 1) * 2048 * 2048, 2048, p.dbh + (size_t)(l - 1) * 2048,
           tile * 64, kD * 128, 128, 0, 16, kD,
           p.kcD + tile, p.pD + (size_t)tile * 4096, p.dcnt + l, lds, &sflag, zl, st);
      }
      waitge(p.dcnt + 4, 32u * (t + 1));
      {  // out layer: tanh -> d_out and dec state
        const float* hin = p.hd0; float* dob = p.dob; float* outp = p.out; const int tt = t;
        auto zl = [=](int b, int k) -> float { return hin[b * 2048 + k]; };
        auto st = [=](int b, int col, float v) {
          outp[(size_t)(b * 16 + tt) * 1024 + col] = v;
          dob[b * 1024 + col] = v;
        };
        p4(p.dWo, 1024, p.dbo, tileO * 64, kO * 64, 64, 1, 32, kO,
           p.kcDo + tileO, p.pD + (size_t)tileO * 8192, p.dcnt + 5, lds, &sflag, zl, st);
      }
    }
  }
}

extern "C" void kernel_launch(void* const* d_in, const int* in_sizes, int n_in,
                              void* d_out, int out_size, void* d_ws, size_t ws_size,
                              hipStream_t stream) {
  // zero the sync-counter region every launch (ws is poisoned once before timing)
  hipMemsetAsync(d_ws, 0, 4096, stream);

  P p;
  p.x    = (const float*)d_in[0];
  p.e0W0 = (const float*)d_in[1];  p.e0b0 = (const float*)d_in[2];
  p.e0W1 = (const float*)d_in[3];  p.e0b1 = (const float*)d_in[4];
  p.e0W2 = (const float*)d_in[5];  p.e0b2 = (const float*)d_in[6];
  p.erW0 = (const float*)d_in[7];  p.erb0 = (const float*)d_in[8];
  p.erW1 = (const float*)d_in[9];  p.erb1 = (const float*)d_in[10];
  p.erW2 = (const float*)d_in[11]; p.erb2 = (const float*)d_in[12];
  p.ffW0 = (const float*)d_in[13]; p.ffb0 = (const float*)d_in[14];
  p.ffW1 = (const float*)d_in[15]; p.ffb1 = (const float*)d_in[16];
  p.dW0  = (const float*)d_in[17]; p.db0  = (const float*)d_in[18];
  p.dWh  = (const float*)d_in[19]; p.dbh  = (const float*)d_in[20];
  p.dWo  = (const float*)d_in[21]; p.dbo  = (const float*)d_in[22];

  float* base = (float*)((char*)d_ws + 4096);
  p.S    = base; base += 2097152;   // 4*16*16*4*512
  p.h1   = base; base += 32768;
  p.h2   = base; base += 32768;
  p.g    = base; base += 2097152;   // 16*64*2048
  p.eo   = base; base += 524288;    // 16*16*4*512
  p.hd0  = base; base += 8192;
  p.hd1  = base; base += 8192;
  p.dob  = base; base += 4096;
  p.pLvl = base; base += 131072;    // 16*8*4*256
  p.pF2  = base; base += 2097152;   // 16*8*4*4096
  p.pD   = base; base += 131072;    // 32*16*256 (== 16*32*256)

  unsigned* c = (unsigned*)d_ws;
  p.aT   = c + 0;   p.bT   = c + 16;  p.cT  = c + 32;
  p.ffg  = c + 48;  p.ffo  = c + 64;  p.dcnt = c + 72;
  p.kcA  = c + 80;  p.kcB  = c + 208; p.kcC = c + 336;
  p.kcF2 = c + 464; p.kcD  = c + 592; p.kcDo = c + 624;

  p.out = (float*)d_out;

  hipLaunchKernelGGL(hrnn, dim3(512), dim3(256), 0, stream, p);
}

// Round 2
// 3005.030 us; speedup vs baseline: 3.6669x; 3.6669x over previous
//
#include <hip/hip_runtime.h>
#include <math.h>
#include <stdint.h>

#define AG __HIP_MEMORY_SCOPE_AGENT
typedef unsigned long long ull;

// ---- cross-XCD-coherent data ops (sc0 sc1, per-address, no cache maintenance)
__device__ __forceinline__ float ld4(const float* p) {
  return __hip_atomic_load(p, __ATOMIC_RELAXED, AG);
}
__device__ __forceinline__ void st4(float* p, float v) {
  __hip_atomic_store(p, v, __ATOMIC_RELAXED, AG);
}
__device__ __forceinline__ ull ld8(const float* p) {
  return __hip_atomic_load((const ull*)p, __ATOMIC_RELAXED, AG);
}
__device__ __forceinline__ void fence_vm() {
  asm volatile("s_waitcnt vmcnt(0)" ::: "memory");
}
// release-flag: drain this wave's (write-through) stores, then bump counter
__device__ __forceinline__ void sigrel(unsigned* c) {
  fence_vm();
  __hip_atomic_fetch_add(c, 1u, __ATOMIC_RELAXED, AG);
}
__device__ __forceinline__ void waitge(unsigned* c, unsigned tgt) {
  if (threadIdx.x == 0) {
    while ((int)(__hip_atomic_load(c, __ATOMIC_RELAXED, AG) - tgt) < 0)
      __builtin_amdgcn_s_sleep(2);
  }
  __syncthreads();
}
__device__ __forceinline__ void wr2(float* d, ull v) {
  d[0] = __uint_as_float((unsigned)v);
  d[1] = __uint_as_float((unsigned)(v >> 32));
}
__device__ __forceinline__ float act_apply(int act, float v) {
  if (act == 0) {  // jax.nn.gelu (tanh approx)
    float v3 = v * v * v;
    return 0.5f * v * (1.0f + tanhf(0.7978845608028654f * (v + 0.044715f * v3)));
  }
  if (act == 1) return tanhf(v);
  return v;
}

// ---------------- P4: rows=4 matmul stage -------------------------------
// 64-col tile, K-chunk [k0,k0+chunk). Internal 4-way K split over waves.
// KC>1: partial + last-arriver deterministic reduce.
template <int KC, class ZL8, class ST>
__device__ void p4(const float* __restrict__ W, int ldw, const float* __restrict__ bias,
                   int c0, int k0, int chunk, int act, int kc,
                   unsigned* kcCnt, float* part, unsigned* stageCnt,
                   float* lds, unsigned* sflag, ZL8&& zl8, ST&& store) {
  const int tid = threadIdx.x;
  __syncthreads();  // protect LDS reuse across stages
  const int cp = chunk >> 1;  // pairs per row
  for (int i = tid; i < 4 * cp; i += 256) {
    int b = i / cp, kp = i - b * cp;
    ull v = zl8(b, (k0 >> 1) + kp);
    wr2(&lds[b * chunk + 2 * kp], v);
  }
  __syncthreads();
  const int j = tid & 63, kq = tid >> 6;
  const int sub = chunk >> 2;
  float a0 = 0.f, a1 = 0.f, a2 = 0.f, a3 = 0.f;
  const float* wp = W + (size_t)(k0 + kq * sub) * ldw + (c0 + j);
  const float* z0 = lds + kq * sub;
  const float* z1 = z0 + chunk;
  const float* z2 = z1 + chunk;
  const float* z3 = z2 + chunk;
#pragma unroll 4
  for (int kk = 0; kk < sub; ++kk) {
    float wv = wp[(size_t)kk * ldw];
    a0 = fmaf(z0[kk], wv, a0);
    a1 = fmaf(z1[kk], wv, a1);
    a2 = fmaf(z2[kk], wv, a2);
    a3 = fmaf(z3[kk], wv, a3);
  }
  __syncthreads();
  float* red = lds;  // [4q][64j][4b]
  red[tid * 4 + 0] = a0; red[tid * 4 + 1] = a1;
  red[tid * 4 + 2] = a2; red[tid * 4 + 3] = a3;
  __syncthreads();
  const int jj = tid & 63, bb = tid >> 6;
  float v = red[jj * 4 + bb] + red[256 + jj * 4 + bb] +
            red[512 + jj * 4 + bb] + red[768 + jj * 4 + bb];
  if constexpr (KC == 1) {
    v += bias[c0 + jj];
    v = act_apply(act, v);
    store(bb, c0 + jj, v);
    fence_vm();
    __syncthreads();
    if (tid == 0) sigrel(stageCnt);
  } else {
    st4(&part[kc * 256 + jj * 4 + bb], v);
    fence_vm();
    __syncthreads();
    if (tid == 0) {
      unsigned old = __hip_atomic_fetch_add(kcCnt, 1u, __ATOMIC_RELAXED, AG);
      *sflag = (old == (unsigned)(KC - 1)) ? 1u : 0u;
    }
    __syncthreads();
    if (*sflag) {
      float s = 0.f;
#pragma unroll
      for (int q = 0; q < KC; ++q) s += ld4(&part[q * 256 + jj * 4 + bb]);
      s += bias[c0 + jj];
      s = act_apply(act, s);
      store(bb, c0 + jj, s);
      fence_vm();
      __syncthreads();
      if (tid == 0) {
        __hip_atomic_store(kcCnt, 0u, __ATOMIC_RELAXED, AG);
        sigrel(stageCnt);
      }
    }
  }
  __syncthreads();
}

// ---------------- P64: rows=64 tiled GEMM stage (FF) --------------------
// 64x64 tile, K-blocks of 64 in LDS, 4x4 reg tile. Z staged via coherent
// pair loads with whole-line-per-instruction coalescing (8 lanes/row).
template <int KC, class ZL8, class ST>
__device__ void p64(const float* __restrict__ W, int ldw, const float* __restrict__ bias,
                    int c0, int k0, int k1, int act, int kc,
                    unsigned* kcCnt, float* part, unsigned* stageCnt,
                    float* lds, unsigned* sflag, ZL8&& zl8, ST&& store) {
  const int tid = threadIdx.x;
  const int tj = tid & 15, tr = tid >> 4;
  float acc[4][4];
#pragma unroll
  for (int r = 0; r < 4; ++r)
#pragma unroll
    for (int c = 0; c < 4; ++c) acc[r][c] = 0.f;
  float* Wl = lds;            // [64][68]
  float* Zl = lds + 64 * 68;  // [64][65]
  const int wk = tid >> 2, wc = (tid & 3) * 16;
  const int r1 = tid >> 3, c8 = tid & 7;
  for (int kb = k0; kb < k1; kb += 64) {
    __syncthreads();
    {  // W: normal (cached) loads, 64B/thread
      const float* src = W + (size_t)(kb + wk) * ldw + c0 + wc;
      float4 w0 = *(const float4*)(src);
      float4 w1 = *(const float4*)(src + 4);
      float4 w2 = *(const float4*)(src + 8);
      float4 w3 = *(const float4*)(src + 12);
      *(float4*)&Wl[wk * 68 + wc + 0]  = w0;
      *(float4*)&Wl[wk * 68 + wc + 4]  = w1;
      *(float4*)&Wl[wk * 68 + wc + 8]  = w2;
      *(float4*)&Wl[wk * 68 + wc + 12] = w3;
    }
    {  // Z: coherent pair loads; 8 lanes cover one 64B line per instr
      ull v[8];
#pragma unroll
      for (int q = 0; q < 8; ++q) {
        int row = (q < 4) ? r1 : 32 + r1;
        int kp = c8 + 8 * (q & 3);  // pair within block [0,32)
        v[q] = zl8(row, (kb >> 1) + kp);
      }
#pragma unroll
      for (int q = 0; q < 8; ++q) {
        int row = (q < 4) ? r1 : 32 + r1;
        int kp = c8 + 8 * (q & 3);
        wr2(&Zl[row * 65 + 2 * kp], v[q]);
      }
    }
    __syncthreads();
#pragma unroll 4
    for (int kk = 0; kk < 64; ++kk) {
      float4 w4 = *(float4*)&Wl[kk * 68 + tj * 4];
      float zr0 = Zl[(tr * 4 + 0) * 65 + kk];
      float zr1 = Zl[(tr * 4 + 1) * 65 + kk];
      float zr2 = Zl[(tr * 4 + 2) * 65 + kk];
      float zr3 = Zl[(tr * 4 + 3) * 65 + kk];
      acc[0][0] = fmaf(zr0, w4.x, acc[0][0]); acc[0][1] = fmaf(zr0, w4.y, acc[0][1]);
      acc[0][2] = fmaf(zr0, w4.z, acc[0][2]); acc[0][3] = fmaf(zr0, w4.w, acc[0][3]);
      acc[1][0] = fmaf(zr1, w4.x, acc[1][0]); acc[1][1] = fmaf(zr1, w4.y, acc[1][1]);
      acc[1][2] = fmaf(zr1, w4.z, acc[1][2]); acc[1][3] = fmaf(zr1, w4.w, acc[1][3]);
      acc[2][0] = fmaf(zr2, w4.x, acc[2][0]); acc[2][1] = fmaf(zr2, w4.y, acc[2][1]);
      acc[2][2] = fmaf(zr2, w4.z, acc[2][2]); acc[2][3] = fmaf(zr2, w4.w, acc[2][3]);
      acc[3][0] = fmaf(zr3, w4.x, acc[3][0]); acc[3][1] = fmaf(zr3, w4.y, acc[3][1]);
      acc[3][2] = fmaf(zr3, w4.z, acc[3][2]); acc[3][3] = fmaf(zr3, w4.w, acc[3][3]);
    }
  }
  __syncthreads();
  if constexpr (KC == 1) {
#pragma unroll
    for (int r = 0; r < 4; ++r)
#pragma unroll
      for (int c = 0; c < 4; ++c) {
        int col = c0 + tj * 4 + c;
        float v = acc[r][c] + bias[col];
        v = act_apply(act, v);
        store(tr * 4 + r, col, v);
      }
    fence_vm();
    __syncthreads();
    if (tid == 0) sigrel(stageCnt);
  } else {
    float* pp = part + kc * 4096;
#pragma unroll
    for (int r = 0; r < 4; ++r)
#pragma unroll
      for (int c = 0; c < 4; ++c)
        st4(&pp[(tr * 4 + r) * 64 + tj * 4 + c], acc[r][c]);
    fence_vm();
    __syncthreads();
    if (tid == 0) {
      unsigned old = __hip_atomic_fetch_add(kcCnt, 1u, __ATOMIC_RELAXED, AG);
      *sflag = (old == (unsigned)(KC - 1)) ? 1u : 0u;
    }
    __syncthreads();
    if (*sflag) {
      for (int r = 0; r < 4; ++r)
        for (int c = 0; c < 4; ++c) {
          int idx = (tr * 4 + r) * 64 + tj * 4 + c;
          float s = 0.f;
#pragma unroll
          for (int q = 0; q < KC; ++q) s += ld4(&part[q * 4096 + idx]);
          int col = c0 + tj * 4 + c;
          s += bias[col];
          s = act_apply(act, s);
          store(tr * 4 + r, col, s);
        }
      fence_vm();
      __syncthreads();
      if (tid == 0) {
        __hip_atomic_store(kcCnt, 0u, __ATOMIC_RELAXED, AG);
        sigrel(stageCnt);
      }
    }
  }
  __syncthreads();
}

struct P {
  const float *x;
  const float *e0W0, *e0b0, *e0W1, *e0b1, *e0W2, *e0b2;
  const float *erW0, *erb0, *erW1, *erb1, *erW2, *erb2;
  const float *ffW0, *ffb0, *ffW1, *ffb1;
  const float *dW0, *db0, *dWh, *dbh, *dWo, *dbo;
  float *S, *h1, *h2, *g, *eo, *hd0, *hd1, *dob, *pF2, *pD;
  unsigned* cnt;
  float* out;
};

// S layout: S[r][t][e][b][512]
#define S_IDX(r, t, e, b) ((size_t)((((r)*16 + (t)) * 16 + (e)) * 4 + (b)) * 512)

// counter map (unsigned offsets in cnt):
//   aT[e*4+lvl]=0..64  bT=64..128  cT=128..192  ffg[e]=192..208  ffo=208
//   dcnt[6]=216..222  kcF2[e*8+ct]=224..352  kcD[32]=352..384  kcDo[16]=384..400
__global__ __launch_bounds__(256, 2) void hrnn(P p) {
  __shared__ __align__(16) float lds[64 * 68 + 64 * 65];
  __shared__ unsigned sflag;
  const int w = blockIdx.x;
  const int e = w & 15, lvl = (w >> 4) & 3, sub = w >> 6;  // encoder-phase roles
  unsigned* aT = p.cnt + 0 + e * 4 + lvl;
  unsigned* bT = p.cnt + 64 + e * 4 + lvl;
  unsigned* cT = p.cnt + 128 + e * 4 + lvl;

  // ======== ENCODERS: wavefront over (lvl,t); 8 WGs per (e,lvl) ==========
  {
    const float *W0, *B0, *W1, *B1, *W2, *B2;
    int K0;
    if (lvl == 0) {
      W0 = p.e0W0 + (size_t)e * 544 * 512; B0 = p.e0b0 + e * 512;
      W1 = p.e0W1 + (size_t)e * 512 * 512; B1 = p.e0b1 + e * 512;
      W2 = p.e0W2 + (size_t)e * 512 * 512; B2 = p.e0b2 + e * 512;
      K0 = 544;
    } else {
      int ri = (lvl - 1) * 16 + e;
      W0 = p.erW0 + (size_t)ri * 1024 * 512; B0 = p.erb0 + (size_t)ri * 512;
      W1 = p.erW1 + (size_t)ri * 512 * 512;  B1 = p.erb1 + (size_t)ri * 512;
      W2 = p.erW2 + (size_t)ri * 512 * 512;  B2 = p.erb2 + (size_t)ri * 512;
      K0 = 1024;
    }
    float* h1 = p.h1 + (size_t)(e * 4 + lvl) * 4 * 512;
    float* h2 = p.h2 + (size_t)(e * 4 + lvl) * 4 * 512;
    for (int t = 0; t < 16; ++t) {
      if (t) waitge(cT, 8u * t);                                  // own S[t-1]
      if (lvl) waitge(p.cnt + 128 + e * 4 + (lvl - 1), 8u * (t + 1));  // S[lvl-1][t]
      {  // stage A
        const float* x = p.x; const float* S = p.S;
        const int tt = t, ee = e, rr = lvl;
        auto zl = [=](int b, int kp) -> ull {
          if (rr == 0) {
            if (kp < 16) return *(const ull*)(x + ((b * 16 + tt) * 32 + 2 * kp));
            return tt ? ld8(S + S_IDX(0, tt - 1, ee, b) + 2 * kp - 32) : 0ull;
          } else {
            if (kp < 256) return ld8(S + S_IDX(rr - 1, tt, ee, b) + 2 * kp);
            return tt ? ld8(S + S_IDX(rr, tt - 1, ee, b) + 2 * kp - 512) : 0ull;
          }
        };
        auto st = [=](int b, int col, float v) { st4(h1 + b * 512 + col, v); };
        p4<1>(W0, 512, B0, sub * 64, 0, K0, 0, 0, nullptr, nullptr, aT, lds, &sflag, zl, st);
      }
      waitge(aT, 8u * (t + 1));
      {  // stage B
        auto zl = [=](int b, int kp) -> ull { return ld8(h1 + b * 512 + 2 * kp); };
        auto st = [=](int b, int col, float v) { st4(h2 + b * 512 + col, v); };
        p4<1>(W1, 512, B1, sub * 64, 0, 512, 0, 0, nullptr, nullptr, bT, lds, &sflag, zl, st);
      }
      waitge(bT, 8u * (t + 1));
      {  // stage C
        float* S = p.S; const int tt = t, ee = e, rr = lvl;
        auto zl = [=](int b, int kp) -> ull { return ld8(h2 + b * 512 + 2 * kp); };
        auto st = [=](int b, int col, float v) { st4(S + S_IDX(rr, tt, ee, b) + col, v); };
        p4<1>(W2, 512, B2, sub * 64, 0, 512, 1, 0, nullptr, nullptr, cT, lds, &sflag, zl, st);
      }
    }
  }

  // ======== FF1: rows=64 (t,b), K=2048, 32 col-tiles per e ================
  for (int r = 0; r < 4; ++r) waitge(p.cnt + 128 + e * 4 + r, 128u);
  {
    const float* S = p.S; const int ee = e;
    auto zl = [=](int row, int kp) -> ull {
      int k = 2 * kp, tt = row >> 2, b = row & 3, seg = k >> 9;
      return ld8(S + S_IDX(seg, tt, ee, b) + (k & 511));
    };
    float* g = p.g + (size_t)e * 64 * 2048;
    auto st = [=](int row, int col, float v) { st4(g + (size_t)row * 2048 + col, v); };
    int slot = w >> 4;  // 0..31
    p64<1>(p.ffW0 + (size_t)e * 2048 * 2048, 2048, p.ffb0 + e * 2048, slot * 64, 0, 2048,
           0, 0, nullptr, nullptr, p.cnt + 192 + e, lds, &sflag, zl, st);
  }
  waitge(p.cnt + 192 + e, 32u);
  // ======== FF2: K=2048 split 4, 8 col-tiles per e ========================
  {
    int ct = w >> 6, kc2 = (w >> 4) & 3;
    const float* g = p.g + (size_t)e * 64 * 2048;
    auto zl = [=](int row, int kp) -> ull { return ld8(g + (size_t)row * 2048 + 2 * kp); };
    float* eo = p.eo; const int ee = e;
    auto st = [=](int row, int col, float v) {
      int tt = row >> 2, b = row & 3;
      st4(eo + (size_t)((tt * 16 + ee) * 4 + b) * 512 + col, v);
    };
    p64<4>(p.ffW1 + (size_t)e * 2048 * 512, 512, p.ffb1 + e * 512, ct * 64,
           kc2 * 512, (kc2 + 1) * 512, 2, kc2,
           p.cnt + 224 + e * 8 + ct, p.pF2 + (size_t)(e * 8 + ct) * 16384,
           p.cnt + 208, lds, &sflag, zl, st);
  }

  // ======== DECODER: sequential over t =====================================
  waitge(p.cnt + 208, 128u);
  {
    const int tile = w >> 4, kD = w & 15;   // layers 0..4: 32 tiles x 16 kc
    const int tileO = w >> 5, kO = w & 31;  // out: 16 tiles x 32 kc
    unsigned* dcnt = p.cnt + 216;
    for (int t = 0; t < 16; ++t) {
      waitge(dcnt + 5, 16u * t);
      {  // layer 0: z = [encout(8192), dec_s(1024)], K=9216 split 16
        const float* eo = p.eo; const float* dob = p.dob; const int tt = t;
        auto zl = [=](int b, int kp) -> ull {
          int k = 2 * kp;
          if (k < 8192) {
            int e2 = k >> 9;
            return ld8(eo + (size_t)((tt * 16 + e2) * 4 + b) * 512 + (k & 511));
          }
          return tt ? ld8(dob + b * 1024 + (k - 8192)) : 0ull;
        };
        float* hd = p.hd0;
        auto st = [=](int b, int col, float v) { st4(hd + b * 2048 + col, v); };
        p4<16>(p.dW0, 2048, p.db0, tile * 64, kD * 576, 576, 0, kD,
               p.cnt + 352 + tile, p.pD + (size_t)tile * 4096, dcnt + 0, lds, &sflag, zl, st);
      }
      for (int l = 1; l <= 4; ++l) {
        waitge(dcnt + (l - 1), 32u * (t + 1));
        const float* hin = (l & 1) ? p.hd0 : p.hd1;
        float* hout = (l & 1) ? p.hd1 : p.hd0;
        auto zl = [=](int b, int kp) -> ull { return ld8(hin + b * 2048 + 2 * kp); };
        auto st = [=](int b, int col, float v) { st4(hout + b * 2048 + col, v); };
        p4<16>(p.dWh + (size_t)(l - 1) * 2048 * 2048, 2048, p.dbh + (size_t)(l - 1) * 2048,
               tile * 64, kD * 128, 128, 0, kD,
               p.cnt + 352 + tile, p.pD + (size_t)tile * 4096, dcnt + l, lds, &sflag, zl, st);
      }
      waitge(dcnt + 4, 32u * (t + 1));
      {  // out layer: tanh -> d_out and dec state
        const float* hin = p.hd0; float* dob = p.dob; float* outp = p.out; const int tt = t;
        auto zl = [=](int b, int kp) -> ull { return ld8(hin + b * 2048 + 2 * kp); };
        auto st = [=](int b, int col, float v) {
          outp[(size_t)(b * 16 + tt) * 1024 + col] = v;  // host-visible, normal store
          st4(dob + b * 1024 + col, v);
        };
        p4<32>(p.dWo, 1024, p.dbo, tileO * 64, kO * 64, 64, 1, kO,
               p.cnt + 384 + tileO, p.pD + (size_t)tileO * 8192, dcnt + 5, lds, &sflag, zl, st);
      }
    }
  }
}

extern "C" void kernel_launch(void* const* d_in, const int* in_sizes, int n_in,
                              void* d_out, int out_size, void* d_ws, size_t ws_size,
                              hipStream_t stream) {
  hipMemsetAsync(d_ws, 0, 4096, stream);  // zero sync counters each launch

  P p;
  p.x    = (const float*)d_in[0];
  p.e0W0 = (const float*)d_in[1];  p.e0b0 = (const float*)d_in[2];
  p.e0W1 = (const float*)d_in[3];  p.e0b1 = (const float*)d_in[4];
  p.e0W2 = (const float*)d_in[5];  p.e0b2 = (const float*)d_in[6];
  p.erW0 = (const float*)d_in[7];  p.erb0 = (const float*)d_in[8];
  p.erW1 = (const float*)d_in[9];  p.erb1 = (const float*)d_in[10];
  p.erW2 = (const float*)d_in[11]; p.erb2 = (const float*)d_in[12];
  p.ffW0 = (const float*)d_in[13]; p.ffb0 = (const float*)d_in[14];
  p.ffW1 = (const float*)d_in[15]; p.ffb1 = (const float*)d_in[16];
  p.dW0  = (const float*)d_in[17]; p.db0  = (const float*)d_in[18];
  p.dWh  = (const float*)d_in[19]; p.dbh  = (const float*)d_in[20];
  p.dWo  = (const float*)d_in[21]; p.dbo  = (const float*)d_in[22];

  float* base = (float*)((char*)d_ws + 4096);
  p.S   = base; base += 2097152;  // 4*16*16*4*512
  p.h1  = base; base += 131072;   // 16*4*4*512
  p.h2  = base; base += 131072;
  p.g   = base; base += 2097152;  // 16*64*2048
  p.eo  = base; base += 524288;   // 16*16*4*512
  p.hd0 = base; base += 8192;
  p.hd1 = base; base += 8192;
  p.dob = base; base += 4096;
  p.pF2 = base; base += 2097152;  // 16*8*4*4096
  p.pD  = base; base += 131072;   // 32*16*256 == 16*32*256

  p.cnt = (unsigned*)d_ws;
  p.out = (float*)d_out;

  hipLaunchKernelGGL(hrnn, dim3(512), dim3(256), 0, stream, p);
}

// Round 3
// 2717.559 us; speedup vs baseline: 4.0548x; 1.1058x over previous
//
#include <hip/hip_runtime.h>
#include <math.h>
#include <stdint.h>

#define AG __HIP_MEMORY_SCOPE_AGENT
typedef unsigned long long ull;

// ---- cross-XCD-coherent data ops (per-address at MALL, no cache maintenance)
__device__ __forceinline__ float ld4(const float* p) {
  return __hip_atomic_load(p, __ATOMIC_RELAXED, AG);
}
__device__ __forceinline__ void st4(float* p, float v) {
  __hip_atomic_store(p, v, __ATOMIC_RELAXED, AG);
}
__device__ __forceinline__ ull ld8(const float* p) {
  return __hip_atomic_load((const ull*)p, __ATOMIC_RELAXED, AG);
}
__device__ __forceinline__ void fence_vm() {
  asm volatile("s_waitcnt vmcnt(0)" ::: "memory");
}
__device__ __forceinline__ void waitge(unsigned* c, unsigned tgt) {
  if (threadIdx.x == 0) {
    while ((int)(__hip_atomic_load(c, __ATOMIC_RELAXED, AG) - tgt) < 0)
      __builtin_amdgcn_s_sleep(1);
  }
  __syncthreads();
}
// poll own replica line (<=8 pollers per line)
__device__ __forceinline__ void wait_epoch(unsigned* line, unsigned epoch) {
  if (threadIdx.x == 0) {
    while ((int)(__hip_atomic_load(line, __ATOMIC_RELAXED, AG) - epoch) < 0)
      __builtin_amdgcn_s_sleep(1);
  }
  __syncthreads();
}
__device__ __forceinline__ void wr2(float* d, ull v) {
  d[0] = __uint_as_float((unsigned)v);
  d[1] = __uint_as_float((unsigned)(v >> 32));
}
__device__ __forceinline__ float act_apply(int act, float v) {
  if (act == 0) {  // jax.nn.gelu (tanh approx)
    float v3 = v * v * v;
    return 0.5f * v * (1.0f + tanhf(0.7978845608028654f * (v + 0.044715f * v3)));
  }
  if (act == 1) return tanhf(v);
  return v;
}

// stage signal: all callers did {stores; fence_vm(); __syncthreads();} first.
// tid0 bumps stageCnt; if it was the bcT-th arrival, wave0 broadcasts epoch
// to 64 replica lines (one store per lane).
__device__ __forceinline__ void stage_signal(unsigned* stageCnt, unsigned bcT,
                                             unsigned* flag, unsigned epoch,
                                             unsigned* sflag) {
  const int tid = threadIdx.x;
  if (tid == 0) {
    unsigned old = __hip_atomic_fetch_add(stageCnt, 1u, __ATOMIC_RELAXED, AG);
    *sflag = (bcT && old == bcT - 1) ? 1u : 0u;
  }
  __syncthreads();
  if (*sflag) {
    if (tid < 64) __hip_atomic_store(flag + tid * 16, epoch, __ATOMIC_RELAXED, AG);
  }
  __syncthreads();
}

// ---------------- P4: rows=4 matmul stage -------------------------------
// 64-col tile, K-chunk [k0,k0+chunk). Internal 4-way K split over waves.
// KC>1: partial + last-arriver (cumulative kcTgt) deterministic reduce.
template <int KC, class ZL8, class ST>
__device__ void p4(const float* __restrict__ W, int ldw, const float* __restrict__ bias,
                   int c0, int k0, int chunk, int act, int kc, unsigned kcTgt,
                   unsigned* kcCnt, float* part,
                   unsigned* stageCnt, unsigned bcT, unsigned* flag, unsigned epoch,
                   float* lds, unsigned* sflag, ZL8&& zl8, ST&& store) {
  const int tid = threadIdx.x;
  __syncthreads();  // protect LDS reuse across stages
  const int cp = chunk >> 1;  // pairs per row
  for (int i = tid; i < 4 * cp; i += 256) {
    int b = i / cp, kp = i - b * cp;
    ull v = zl8(b, (k0 >> 1) + kp);
    wr2(&lds[b * chunk + 2 * kp], v);
  }
  __syncthreads();
  const int j = tid & 63, kq = tid >> 6;
  const int sub = chunk >> 2;
  float a0 = 0.f, a1 = 0.f, a2 = 0.f, a3 = 0.f;
  const float* wp = W + (size_t)(k0 + kq * sub) * ldw + (c0 + j);
  const float* z0 = lds + kq * sub;
  const float* z1 = z0 + chunk;
  const float* z2 = z1 + chunk;
  const float* z3 = z2 + chunk;
#pragma unroll 8
  for (int kk = 0; kk < sub; ++kk) {
    float wv = wp[(size_t)kk * ldw];
    a0 = fmaf(z0[kk], wv, a0);
    a1 = fmaf(z1[kk], wv, a1);
    a2 = fmaf(z2[kk], wv, a2);
    a3 = fmaf(z3[kk], wv, a3);
  }
  __syncthreads();
  float* red = lds;  // [4q][64j][4b]
  red[tid * 4 + 0] = a0; red[tid * 4 + 1] = a1;
  red[tid * 4 + 2] = a2; red[tid * 4 + 3] = a3;
  __syncthreads();
  const int jj = tid & 63, bb = tid >> 6;
  float v = red[jj * 4 + bb] + red[256 + jj * 4 + bb] +
            red[512 + jj * 4 + bb] + red[768 + jj * 4 + bb];
  if constexpr (KC == 1) {
    v += bias[c0 + jj];
    v = act_apply(act, v);
    store(bb, c0 + jj, v);
    fence_vm();
    __syncthreads();
    stage_signal(stageCnt, bcT, flag, epoch, sflag);
  } else {
    st4(&part[kc * 256 + jj * 4 + bb], v);
    fence_vm();
    __syncthreads();
    if (tid == 0) {
      unsigned old = __hip_atomic_fetch_add(kcCnt, 1u, __ATOMIC_RELAXED, AG);
      *sflag = (old == kcTgt - 1) ? 1u : 0u;
    }
    __syncthreads();
    if (*sflag) {
      float s = 0.f;
#pragma unroll
      for (int q = 0; q < KC; ++q) s += ld4(&part[q * 256 + jj * 4 + bb]);
      s += bias[c0 + jj];
      s = act_apply(act, s);
      store(bb, c0 + jj, s);
      fence_vm();
      __syncthreads();
      stage_signal(stageCnt, bcT, flag, epoch, sflag);
    }
  }
  __syncthreads();
}

// ---------------- P64: rows=64 tiled GEMM stage (FF) --------------------
template <int KC, class ZL8, class ST>
__device__ void p64(const float* __restrict__ W, int ldw, const float* __restrict__ bias,
                    int c0, int k0, int k1, int act, int kc, unsigned kcTgt,
                    unsigned* kcCnt, float* part,
                    unsigned* stageCnt, unsigned bcT, unsigned* flag, unsigned epoch,
                    float* lds, unsigned* sflag, ZL8&& zl8, ST&& store) {
  const int tid = threadIdx.x;
  const int tj = tid & 15, tr = tid >> 4;
  float acc[4][4];
#pragma unroll
  for (int r = 0; r < 4; ++r)
#pragma unroll
    for (int c = 0; c < 4; ++c) acc[r][c] = 0.f;
  float* Wl = lds;            // [64][68]
  float* Zl = lds + 64 * 68;  // [64][65]
  const int wk = tid >> 2, wc = (tid & 3) * 16;
  const int r1 = tid >> 3, c8 = tid & 7;
  for (int kb = k0; kb < k1; kb += 64) {
    __syncthreads();
    {  // W: normal (cached) loads, 64B/thread
      const float* src = W + (size_t)(kb + wk) * ldw + c0 + wc;
      float4 w0 = *(const float4*)(src);
      float4 w1 = *(const float4*)(src + 4);
      float4 w2 = *(const float4*)(src + 8);
      float4 w3 = *(const float4*)(src + 12);
      *(float4*)&Wl[wk * 68 + wc + 0]  = w0;
      *(float4*)&Wl[wk * 68 + wc + 4]  = w1;
      *(float4*)&Wl[wk * 68 + wc + 8]  = w2;
      *(float4*)&Wl[wk * 68 + wc + 12] = w3;
    }
    {  // Z: coherent pair loads; 8 lanes cover one 64B line per instr
      ull v[8];
#pragma unroll
      for (int q = 0; q < 8; ++q) {
        int row = (q < 4) ? r1 : 32 + r1;
        int kp = c8 + 8 * (q & 3);
        v[q] = zl8(row, (kb >> 1) + kp);
      }
#pragma unroll
      for (int q = 0; q < 8; ++q) {
        int row = (q < 4) ? r1 : 32 + r1;
        int kp = c8 + 8 * (q & 3);
        wr2(&Zl[row * 65 + 2 * kp], v[q]);
      }
    }
    __syncthreads();
#pragma unroll 4
    for (int kk = 0; kk < 64; ++kk) {
      float4 w4 = *(float4*)&Wl[kk * 68 + tj * 4];
      float zr0 = Zl[(tr * 4 + 0) * 65 + kk];
      float zr1 = Zl[(tr * 4 + 1) * 65 + kk];
      float zr2 = Zl[(tr * 4 + 2) * 65 + kk];
      float zr3 = Zl[(tr * 4 + 3) * 65 + kk];
      acc[0][0] = fmaf(zr0, w4.x, acc[0][0]); acc[0][1] = fmaf(zr0, w4.y, acc[0][1]);
      acc[0][2] = fmaf(zr0, w4.z, acc[0][2]); acc[0][3] = fmaf(zr0, w4.w, acc[0][3]);
      acc[1][0] = fmaf(zr1, w4.x, acc[1][0]); acc[1][1] = fmaf(zr1, w4.y, acc[1][1]);
      acc[1][2] = fmaf(zr1, w4.z, acc[1][2]); acc[1][3] = fmaf(zr1, w4.w, acc[1][3]);
      acc[2][0] = fmaf(zr2, w4.x, acc[2][0]); acc[2][1] = fmaf(zr2, w4.y, acc[2][1]);
      acc[2][2] = fmaf(zr2, w4.z, acc[2][2]); acc[2][3] = fmaf(zr2, w4.w, acc[2][3]);
      acc[3][0] = fmaf(zr3, w4.x, acc[3][0]); acc[3][1] = fmaf(zr3, w4.y, acc[3][1]);
      acc[3][2] = fmaf(zr3, w4.z, acc[3][2]); acc[3][3] = fmaf(zr3, w4.w, acc[3][3]);
    }
  }
  __syncthreads();
  if constexpr (KC == 1) {
#pragma unroll
    for (int r = 0; r < 4; ++r)
#pragma unroll
      for (int c = 0; c < 4; ++c) {
        int col = c0 + tj * 4 + c;
        float v = acc[r][c] + bias[col];
        v = act_apply(act, v);
        store(tr * 4 + r, col, v);
      }
    fence_vm();
    __syncthreads();
    stage_signal(stageCnt, bcT, flag, epoch, sflag);
  } else {
    float* pp = part + kc * 4096;
#pragma unroll
    for (int r = 0; r < 4; ++r)
#pragma unroll
      for (int c = 0; c < 4; ++c)
        st4(&pp[(tr * 4 + r) * 64 + tj * 4 + c], acc[r][c]);
    fence_vm();
    __syncthreads();
    if (tid == 0) {
      unsigned old = __hip_atomic_fetch_add(kcCnt, 1u, __ATOMIC_RELAXED, AG);
      *sflag = (old == kcTgt - 1) ? 1u : 0u;
    }
    __syncthreads();
    if (*sflag) {
      for (int r = 0; r < 4; ++r)
        for (int c = 0; c < 4; ++c) {
          int idx = (tr * 4 + r) * 64 + tj * 4 + c;
          float s = 0.f;
#pragma unroll
          for (int q = 0; q < KC; ++q) s += ld4(&part[q * 4096 + idx]);
          int col = c0 + tj * 4 + c;
          s += bias[col];
          s = act_apply(act, s);
          store(tr * 4 + r, col, s);
        }
      fence_vm();
      __syncthreads();
      stage_signal(stageCnt, bcT, flag, epoch, sflag);
    }
  }
  __syncthreads();
}

struct P {
  const float *x;
  const float *e0W0, *e0b0, *e0W1, *e0b1, *e0W2, *e0b2;
  const float *erW0, *erb0, *erW1, *erb1, *erW2, *erb2;
  const float *ffW0, *ffb0, *ffW1, *ffb1;
  const float *dW0, *db0, *dWh, *dbh, *dWo, *dbo;
  float *S, *h1, *h2, *g, *eo, *hd0, *hd1, *dob, *pF2, *pD;
  unsigned* cnt;
  float* out;
};

// S layout: S[r][t][e][b][512]
#define S_IDX(r, t, e, b) ((size_t)((((r)*16 + (t)) * 16 + (e)) * 4 + (b)) * 512)

// counter map: each logical counter occupies its own 64B line (16 u32).
// indices are in counter units; cptr(i) = cnt + i*16.
#define C_A 0      // aT[e*4+lvl]   (64)
#define C_B 64     // bT            (64)
#define C_C 128    // cT            (64)
#define C_FFG 192  // ffg[e]        (16)
#define C_KF2 208  // kcF2[e*8+ct]  (128)
#define C_FFO 336  // ffo           (1)
#define C_DC 344   // dcnt[6]       (6)
#define C_KD 352   // kcD[32]       (32)
#define C_KDO 384  // kcDo[16]      (16)
#define C_FFLAG 400  // flagFF      (64 lines)
#define C_OFLAG 464  // flagOut     (64 lines)
#define C_DFLAG 528  // flagD[5]    (5*64 lines)

__global__ __launch_bounds__(256, 2) void hrnn(P p) {
  __shared__ __align__(16) float lds[64 * 68 + 64 * 65];
  __shared__ unsigned sflag;
  const int w = blockIdx.x;
  const int e = w & 15, lvl = (w >> 4) & 3, sub = w >> 6;  // encoder roles
  auto cptr = [&](int i) { return p.cnt + (size_t)i * 16; };
  unsigned* myline_ff = cptr(C_FFLAG + (w & 63));
  unsigned* myline_out = cptr(C_OFLAG + (w & 63));

  // ======== ENCODERS: wavefront over (lvl,t); 8 WGs per (e,lvl) ==========
  {
    const float *W0, *B0, *W1, *B1, *W2, *B2;
    int K0;
    if (lvl == 0) {
      W0 = p.e0W0 + (size_t)e * 544 * 512; B0 = p.e0b0 + e * 512;
      W1 = p.e0W1 + (size_t)e * 512 * 512; B1 = p.e0b1 + e * 512;
      W2 = p.e0W2 + (size_t)e * 512 * 512; B2 = p.e0b2 + e * 512;
      K0 = 544;
    } else {
      int ri = (lvl - 1) * 16 + e;
      W0 = p.erW0 + (size_t)ri * 1024 * 512; B0 = p.erb0 + (size_t)ri * 512;
      W1 = p.erW1 + (size_t)ri * 512 * 512;  B1 = p.erb1 + (size_t)ri * 512;
      W2 = p.erW2 + (size_t)ri * 512 * 512;  B2 = p.erb2 + (size_t)ri * 512;
      K0 = 1024;
    }
    unsigned* aT = cptr(C_A + e * 4 + lvl);
    unsigned* bT = cptr(C_B + e * 4 + lvl);
    unsigned* cT = cptr(C_C + e * 4 + lvl);
    float* h1 = p.h1 + (size_t)(e * 4 + lvl) * 4 * 512;
    float* h2 = p.h2 + (size_t)(e * 4 + lvl) * 4 * 512;
    for (int t = 0; t < 16; ++t) {
      if (t) waitge(cT, 8u * t);
      if (lvl) waitge(cptr(C_C + e * 4 + lvl - 1), 8u * (t + 1));
      {  // stage A
        const float* x = p.x; const float* S = p.S;
        const int tt = t, ee = e, rr = lvl;
        auto zl = [=](int b, int kp) -> ull {
          if (rr == 0) {
            if (kp < 16) return *(const ull*)(x + ((b * 16 + tt) * 32 + 2 * kp));
            return tt ? ld8(S + S_IDX(0, tt - 1, ee, b) + 2 * kp - 32) : 0ull;
          } else {
            if (kp < 256) return ld8(S + S_IDX(rr - 1, tt, ee, b) + 2 * kp);
            return tt ? ld8(S + S_IDX(rr, tt - 1, ee, b) + 2 * kp - 512) : 0ull;
          }
        };
        auto st = [=](int b, int col, float v) { st4(h1 + b * 512 + col, v); };
        p4<1>(W0, 512, B0, sub * 64, 0, K0, 0, 0, 0, nullptr, nullptr,
              aT, 0, nullptr, 0, lds, &sflag, zl, st);
      }
      waitge(aT, 8u * (t + 1));
      {  // stage B
        auto zl = [=](int b, int kp) -> ull { return ld8(h1 + b * 512 + 2 * kp); };
        auto st = [=](int b, int col, float v) { st4(h2 + b * 512 + col, v); };
        p4<1>(W1, 512, B1, sub * 64, 0, 512, 0, 0, 0, nullptr, nullptr,
              bT, 0, nullptr, 0, lds, &sflag, zl, st);
      }
      waitge(bT, 8u * (t + 1));
      {  // stage C
        float* S = p.S; const int tt = t, ee = e, rr = lvl;
        auto zl = [=](int b, int kp) -> ull { return ld8(h2 + b * 512 + 2 * kp); };
        auto st = [=](int b, int col, float v) { st4(S + S_IDX(rr, tt, ee, b) + col, v); };
        p4<1>(W2, 512, B2, sub * 64, 0, 512, 1, 0, 0, nullptr, nullptr,
              cT, 0, nullptr, 0, lds, &sflag, zl, st);
      }
    }
  }

  // ======== FF1: rows=64 (t,b), K=2048, 32 col-tiles per e ================
  for (int r = 0; r < 4; ++r) waitge(cptr(C_C + e * 4 + r), 128u);
  {
    const float* S = p.S; const int ee = e;
    auto zl = [=](int row, int kp) -> ull {
      int k = 2 * kp, tt = row >> 2, b = row & 3, seg = k >> 9;
      return ld8(S + S_IDX(seg, tt, ee, b) + (k & 511));
    };
    float* g = p.g + (size_t)e * 64 * 2048;
    auto st = [=](int row, int col, float v) { st4(g + (size_t)row * 2048 + col, v); };
    int slot = w >> 4;
    p64<1>(p.ffW0 + (size_t)e * 2048 * 2048, 2048, p.ffb0 + e * 2048, slot * 64, 0, 2048,
           0, 0, 0, nullptr, nullptr, cptr(C_FFG + e), 0, nullptr, 0,
           lds, &sflag, zl, st);
  }
  waitge(cptr(C_FFG + e), 32u);
  // ======== FF2: K=2048 split 4; completion broadcast to flagFF ===========
  {
    int ct = w >> 6, kc2 = (w >> 4) & 3;
    const float* g = p.g + (size_t)e * 64 * 2048;
    auto zl = [=](int row, int kp) -> ull { return ld8(g + (size_t)row * 2048 + 2 * kp); };
    float* eo = p.eo; const int ee = e;
    auto st = [=](int row, int col, float v) {
      int tt = row >> 2, b = row & 3;
      st4(eo + (size_t)((tt * 16 + ee) * 4 + b) * 512 + col, v);
    };
    p64<4>(p.ffW1 + (size_t)e * 2048 * 512, 512, p.ffb1 + e * 512, ct * 64,
           kc2 * 512, (kc2 + 1) * 512, 2, kc2, 4,
           cptr(C_KF2 + e * 8 + ct), p.pF2 + (size_t)(e * 8 + ct) * 16384,
           cptr(C_FFO), 128, cptr(C_FFLAG), 1, lds, &sflag, zl, st);
  }

  // ======== DECODER: sequential over t, broadcast-flag sync ===============
  wait_epoch(myline_ff, 1u);
  {
    const int tile = w >> 4, kD = w & 15;   // layers 0..4: 32 tiles x 16 kc
    const int tileO = w >> 5, kO = w & 31;  // out: 16 tiles x 32 kc
    for (int t = 0; t < 16; ++t) {
      if (t) wait_epoch(myline_out, (unsigned)t);
      {  // layer 0: z = [encout(8192), dec_s(1024)], K=9216 split 16
        const float* eo = p.eo; const float* dob = p.dob; const int tt = t;
        auto zl = [=](int b, int kp) -> ull {
          int k = 2 * kp;
          if (k < 8192) {
            int e2 = k >> 9;
            return ld8(eo + (size_t)((tt * 16 + e2) * 4 + b) * 512 + (k & 511));
          }
          return tt ? ld8(dob + b * 1024 + (k - 8192)) : 0ull;
        };
        float* hd = p.hd0;
        auto st = [=](int b, int col, float v) { st4(hd + b * 2048 + col, v); };
        p4<16>(p.dW0, 2048, p.db0, tile * 64, kD * 576, 576, 0, kD, 80u * t + 16u,
               cptr(C_KD + tile), p.pD + (size_t)tile * 4096,
               cptr(C_DC + 0), 32u * (t + 1), cptr(C_DFLAG + 0 * 64), (unsigned)(t + 1),
               lds, &sflag, zl, st);
      }
      for (int l = 1; l <= 4; ++l) {
        wait_epoch(cptr(C_DFLAG + (l - 1) * 64 + (w & 63)), (unsigned)(t + 1));
        const float* hin = (l & 1) ? p.hd0 : p.hd1;
        float* hout = (l & 1) ? p.hd1 : p.hd0;
        auto zl = [=](int b, int kp) -> ull { return ld8(hin + b * 2048 + 2 * kp); };
        auto st = [=](int b, int col, float v) { st4(hout + b * 2048 + col, v); };
        p4<16>(p.dWh + (size_t)(l - 1) * 2048 * 2048, 2048, p.dbh + (size_t)(l - 1) * 2048,
               tile * 64, kD * 128, 128, 0, kD, 80u * t + 16u * (l + 1),
               cptr(C_KD + tile), p.pD + (size_t)tile * 4096,
               cptr(C_DC + l), 32u * (t + 1), cptr(C_DFLAG + l * 64), (unsigned)(t + 1),
               lds, &sflag, zl, st);
      }
      wait_epoch(cptr(C_DFLAG + 4 * 64 + (w & 63)), (unsigned)(t + 1));
      {  // out layer: tanh -> d_out and dec state
        const float* hin = p.hd0; float* dob = p.dob; float* outp = p.out; const int tt = t;
        auto zl = [=](int b, int kp) -> ull { return ld8(hin + b * 2048 + 2 * kp); };
        auto st = [=](int b, int col, float v) {
          outp[(size_t)(b * 16 + tt) * 1024 + col] = v;  // host-visible
          st4(dob + b * 1024 + col, v);
        };
        p4<32>(p.dWo, 1024, p.dbo, tileO * 64, kO * 64, 64, 1, kO, 32u * (t + 1),
               cptr(C_KDO + tileO), p.pD + (size_t)tileO * 8192,
               cptr(C_DC + 5), 16u * (t + 1), cptr(C_OFLAG), (unsigned)(t + 1),
               lds, &sflag, zl, st);
      }
    }
  }
}

extern "C" void kernel_launch(void* const* d_in, const int* in_sizes, int n_in,
                              void* d_out, int out_size, void* d_ws, size_t ws_size,
                              hipStream_t stream) {
  hipMemsetAsync(d_ws, 0, 65536, stream);  // zero padded counters + flags

  P p;
  p.x    = (const float*)d_in[0];
  p.e0W0 = (const float*)d_in[1];  p.e0b0 = (const float*)d_in[2];
  p.e0W1 = (const float*)d_in[3];  p.e0b1 = (const float*)d_in[4];
  p.e0W2 = (const float*)d_in[5];  p.e0b2 = (const float*)d_in[6];
  p.erW0 = (const float*)d_in[7];  p.erb0 = (const float*)d_in[8];
  p.erW1 = (const float*)d_in[9];  p.erb1 = (const float*)d_in[10];
  p.erW2 = (const float*)d_in[11]; p.erb2 = (const float*)d_in[12];
  p.ffW0 = (const float*)d_in[13]; p.ffb0 = (const float*)d_in[14];
  p.ffW1 = (const float*)d_in[15]; p.ffb1 = (const float*)d_in[16];
  p.dW0  = (const float*)d_in[17]; p.db0  = (const float*)d_in[18];
  p.dWh  = (const float*)d_in[19]; p.dbh  = (const float*)d_in[20];
  p.dWo  = (const float*)d_in[21]; p.dbo  = (const float*)d_in[22];

  float* base = (float*)((char*)d_ws + 65536);
  p.S   = base; base += 2097152;  // 4*16*16*4*512
  p.h1  = base; base += 131072;   // 16*4*4*512
  p.h2  = base; base += 131072;
  p.g   = base; base += 2097152;  // 16*64*2048
  p.eo  = base; base += 524288;   // 16*16*4*512
  p.hd0 = base; base += 8192;
  p.hd1 = base; base += 8192;
  p.dob = base; base += 4096;
  p.pF2 = base; base += 2097152;  // 16*8*4*4096
  p.pD  = base; base += 131072;   // 32*16*256 == 16*32*256

  p.cnt = (unsigned*)d_ws;
  p.out = (float*)d_out;

  hipLaunchKernelGGL(hrnn, dim3(512), dim3(256), 0, stream, p);
}